// Round 6
// baseline (249.149 us; speedup 1.0000x reference)
//
#include <hip/hip_runtime.h>
#include <stdint.h>

typedef float  v4f __attribute__((ext_vector_type(4)));
typedef short  v4s __attribute__((ext_vector_type(4)));

#define LOG2E 1.44269504088896340736f
#define LN2   0.69314718055994530942f

static __device__ __forceinline__ float fexp2(float x){ return __builtin_amdgcn_exp2f(x); }
static __device__ __forceinline__ float flog2(float x){ return __builtin_amdgcn_logf(x); }

// pack two f32 -> two bf16 (round-half-up) in one dword via v_perm — PROVEN in R1-R4.
// (R5's __builtin_amdgcn_cvt_pk_bf16_f32 produced NaN output; suspected bad lowering.)
static __device__ __forceinline__ unsigned pkbf(float a, float b){
  unsigned ua = __float_as_uint(a) + 0x8000u;
  unsigned ub = __float_as_uint(b) + 0x8000u;
  return __builtin_amdgcn_perm(ub, ua, 0x07060302u);
}
static __device__ __forceinline__ v4s pack4(const v4f& m){
  union { unsigned u[2]; v4s s; } t;
  t.u[0] = pkbf(m.x, m.y);
  t.u[1] = pkbf(m.z, m.w);
  return t.s;
}

static __device__ __forceinline__ v4f mfma16(v4s a, v4s b, v4f c){
#if __has_builtin(__builtin_amdgcn_mfma_f32_16x16x16bf16_1k)
  return __builtin_amdgcn_mfma_f32_16x16x16bf16_1k(a, b, c, 0, 0, 0);
#else
  v4f r = c;
  asm("s_nop 1\n\tv_mfma_f32_16x16x16_bf16 %0, %1, %2, %0\n\ts_nop 7\n\ts_nop 1"
      : "+v"(r) : "v"(a), "v"(b));
  return r;
#endif
}

static __device__ __forceinline__ float sel4(const v4f& e4, int s){
  float a = (s & 1) ? e4.y : e4.x;
  float c = (s & 1) ? e4.w : e4.z;
  return (s & 2) ? c : a;
}

// ---------------- Phase 1 ----------------
// R11: S=256 steps/chunk, C=8 chunks (was 64/32). Same per-step math as the
// proven R7 structure; the kb loop runs 32 octets with #pragma unroll 4 and a
// 4-buffer (kb&3) rotation so every buffer index is compile-time static under
// partial unroll (R8 lesson: runtime-indexed regs -> scratch spill).
// One chain per wave: 4 (batch,chunk) 8x8 transfer-matrix products via one
// 16x16x16 bf16 MFMA (blockdiag(E^T,E^T), 2x2 column-octets).
// Lane roles: n=lane&15, q=lane>>4, qr=q&1 (row half r0=4*qr), cn=n&7 (column),
// matrix mm=((q>>1)<<1)|(n>>3). Recurrence P' = diag(exp(em_t)) * E^T * P.
// D (C-layout) == next B (B-layout) -> zero-shuffle feedback.
// Pipelining: em/tags prefetched 3 octets ahead (4 buffers); exps for octet
// kb+1 computed+written to the LDS parity slot during octet kb. Per-wave DS
// ops are in-order: no barrier. Masks from one per-kb __ballot (tags
// monotone); wave-uniform triage (MFMA always full-EXEC); masked body is
// per-lane cndmask; wave-uniform dead-break skips the chunk remainder.

template<bool MASKED>
__device__ __forceinline__ void chunk_loop(
    const float* __restrict__ emb, const int* __restrict__ tgb, int c,
    const float* s_trans, const float* s_end, float* s_slot,
    v4s afrag, int qr, int r0, int cn, bool lastChunk,
    v4f& master, v4s& bfrag, float& lZ, float& num)
{
  v4f eo[4]; int tc[4], tp[4];

  auto loadK = [&](int kb){                // buffer = kb & 3, always
    const int t0 = kb << 3;
    const int buf = kb & 3;
    eo[buf] = *(const v4f*)(emb + (size_t)(t0 + cn) * 8u);
    tc[buf] = tgb[t0 + cn];
    int ip = t0 + cn - 1;
    if (c == 0 && ip < 0) ip = 0;        // global t=0: value unused
    tp[buf] = tgb[ip];
  };

  auto expwrite = [&](const v4f& e, int par){
    v4f ed;
    ed.x = fexp2(e.x * LOG2E); ed.y = fexp2(e.y * LOG2E);
    ed.z = fexp2(e.z * LOG2E); ed.w = fexp2(e.w * LOG2E);
    *(v4f*)(s_slot + (par << 5) + (cn << 2)) = ed;   // ds_write_b128
  };

  loadK(0); loadK(1); loadK(2);
  expwrite(eo[0], 0);

#pragma unroll 4
  for (int kb = 0; kb < 32; ++kb){
    const int buf = kb & 3;

    // distributed numerator for step t = kb*8 + cn (must precede dead-break:
    // the end_transitions add fires on the first masked step of the batch)
    const bool sk0 = (!MASKED) && (c == 0) && (kb == 0);
    {
      bool act = MASKED ? (tc[buf] != 0) : true;
      if (sk0 && cn == 0) act = false;
      const int s = tc[buf] - 1;
      const float ev = sel4(eo[buf], s);
      num += (act && ((s >> 2) == qr)) ? ev : 0.f;
      const float tv = s_trans[(((tp[buf] - 1) & 7) << 3) + (s & 7)];
      num += (act && (qr == 0)) ? tv : 0.f;
      if (MASKED && (tp[buf] != 0) && (tc[buf] == 0) && (qr == 0))
        num += s_end[tp[buf] - 1];
    }

    // per-kb mask byte from one ballot; tags are monotone -> all-zero kb
    // means every later step is masked too: stop the chunk. Both octets of a
    // matrix see identical bytes, so mb is coherent per matrix.
    unsigned mb = 0xffu;
    bool allAlive = true;                 // wave-uniform
    if (MASKED){
      const unsigned long long bal = __ballot(tc[buf] != 0);
      if (bal == 0ull) break;             // wave-uniform: all 4 matrices dead
      mb = (unsigned)(bal >> (threadIdx.x & 56)) & 0xffu;
      allAlive = (bal == ~0ull);
    }

    // broadcast exps for this octet (written one octet ago)
    v4f e8[8];
    const float* sl = s_slot + ((kb & 1) << 5);
#pragma unroll
    for (int j = 0; j < 8; ++j) e8[j] = *(const v4f*)(sl + (j << 2));

    // exps for next octet -> other parity slot (distance = one full octet);
    // deep prefetch of octet kb+3 em/tags into buffer (kb+3)&3 (free slot)
    if (kb + 1 < 32) expwrite(eo[(kb + 1) & 3], (kb + 1) & 1);
    if (kb + 3 < 32) loadK(kb + 3);

    // 8 recurrence steps — branch is wave-uniform; MFMA always full-EXEC
    if (!MASKED || allAlive){
#pragma unroll
      for (int j = 0; j < 8; ++j){
        if (sk0 && j == 0) continue;     // global t=0 handled in phase 2
        v4f zero = {0.f, 0.f, 0.f, 0.f};
        v4f d = mfma16(afrag, bfrag, zero);
        const v4f e = e8[j];
        master.x = d.x * e.x; master.y = d.y * e.y;
        master.z = d.z * e.z; master.w = d.w * e.w;
        bfrag = pack4(master);
      }
    } else {
#pragma unroll
      for (int j = 0; j < 8; ++j){
        v4f zero = {0.f, 0.f, 0.f, 0.f};
        v4f d = mfma16(afrag, bfrag, zero);
        const v4f e = e8[j];
        const bool v = (mb >> j) & 1u;   // per-lane cndmask, no branch
        master.x = v ? d.x * e.x : master.x;
        master.y = v ? d.y * e.y : master.y;
        master.z = v ? d.z * e.z : master.z;
        master.w = v ? d.w * e.w : master.w;
        bfrag = pack4(master);
      }
    }

    if (kb & 1){                          // renorm every 16 steps (per column)
      float mx = fmaxf(fmaxf(master.x, master.y), fmaxf(master.z, master.w));
      mx = fmaxf(mx, __shfl_xor(mx, 16, 64));
      const float inv = __builtin_amdgcn_rcpf(mx);
      master.x *= inv; master.y *= inv; master.z *= inv; master.w *= inv;
      lZ += flog2(mx);
      bfrag = pack4(master);
    }
  }

  if (MASKED && lastChunk){
    const int lt = tgb[255];              // tag at global t = L-1
    if ((lt != 0) && (qr == 0) && (cn == 0)) num += s_end[lt - 1];
  }
}

__global__ __launch_bounds__(256, 4)
void crf_phase1(const float* __restrict__ em,
                const float* __restrict__ trans,
                const float* __restrict__ endt,
                const int*   __restrict__ tags,
                float* __restrict__ ws,
                float* __restrict__ out)
{
  const int tid  = threadIdx.x;
  const int lane = tid & 63;
  const int n = lane & 15, q = lane >> 4, qr = q & 1, r0 = qr << 2, cn = n & 7;
  const int mm = ((q >> 1) << 1) | (n >> 3);
  const int p  = (blockIdx.x << 4) + ((tid >> 6) << 2) + mm;
  const int c  = p >> 11;                 // chunk id (S=256, C=8)
  const int bm = p & 2047;                // batch id

  if (blockIdx.x == 0 && tid == 0) out[0] = 0.f;   // replaces memset dispatch

  __shared__ float s_trans[64];
  __shared__ float s_end[8];
  __shared__ float s_e[32 * 68];          // 32 groups x (2 slots x 32 + 4 pad)
  if (tid < 64) s_trans[tid] = trans[tid];
  if (tid < 8)  s_end[tid]  = endt[tid];
  __syncthreads();

  // constant A fragment: blockdiag(E^T, E^T); A[m][k], m=n, k=4q+j
  v4s afrag;
  {
    float av[4];
#pragma unroll
    for (int j = 0; j < 4; ++j){
      const int k = (q << 2) + j;
      float v = 0.f;
      if (n < 8 && k < 8)        v = fexp2(s_trans[k * 8 + n] * LOG2E);
      else if (n >= 8 && k >= 8) v = fexp2(s_trans[(k - 8) * 8 + (n - 8)] * LOG2E);
      av[j] = v;
    }
    union { unsigned u[2]; v4s s; } t;
    t.u[0] = pkbf(av[0], av[1]);
    t.u[1] = pkbf(av[2], av[3]);
    afrag = t.s;
  }

  const float* emb = em   + ((size_t)bm * 2048u + (size_t)c * 256u) * 8u + (unsigned)r0;
  const int*   tgb = tags + (size_t)bm * 2048u + (size_t)c * 256u;
  float* s_slot = &s_e[(tid >> 3) * 68];

  // P = identity
  v4f master;
  master.x = (r0 + 0 == cn) ? 1.f : 0.f;
  master.y = (r0 + 1 == cn) ? 1.f : 0.f;
  master.z = (r0 + 2 == cn) ? 1.f : 0.f;
  master.w = (r0 + 3 == cn) ? 1.f : 0.f;
  v4s bfrag = pack4(master);
  float num = 0.f, lZ = 0.f;

  if (c <= 3){                             // steps < 1024: never masked
    chunk_loop<false>(emb, tgb, c, s_trans, s_end, s_slot,
                      afrag, qr, r0, cn, false, master, bfrag, lZ, num);
  } else {
    const bool fz = (tgb[0] == 0);
    if (__ballot(fz) == ~0ull){            // all 4 pairs fully masked: identity
      const int pv = tgb[-1];
      if ((pv != 0) && (qr == 0) && (cn == 0)) num = s_end[pv - 1];
    } else {
      chunk_loop<true>(emb, tgb, c, s_trans, s_end, s_slot,
                       afrag, qr, r0, cn, (c == 7), master, bfrag, lZ, num);
    }
  }

  // ---- store, [c][entry-pair][b] layout (phase-2 coalescing) ----
  float2* ws2 = ((float2*)ws) + (size_t)c * 40u * 2048u + (unsigned)bm;
  const int e0 = (cn << 3) + r0;           // entry e = col*8 + row (even)
  float2 v01; v01.x = master.x; v01.y = master.y;
  float2 v23; v23.x = master.z; v23.y = master.w;
  ws2[(size_t)(e0 >> 1) * 2048u]       = v01;
  ws2[(size_t)((e0 >> 1) + 1) * 2048u] = v23;
  if (qr == 0)
    ((float*)(ws2 + (size_t)((64 + cn) >> 1) * 2048u))[cn & 1] = lZ;
  num += __shfl_xor(num, 1, 64);
  num += __shfl_xor(num, 2, 64);
  num += __shfl_xor(num, 4, 64);
  num += __shfl_xor(num, 16, 64);
  if (qr == 0 && cn == 0)
    ((float*)(ws2 + (size_t)36 * 2048u))[0] = num;
}

// ---------------- Phase 2: per-batch combine of chunk matrices ----------------
// 8 lanes per batch (lane j holds alpha[row j]); 256 one-wave blocks.
// R11: only 8 serial iterations now (C=8). Evidence so far: phase2's cost
// scales with serial iteration count (~2us/iter of exposed latency at 1
// wave/CU), not with per-iteration content — R8 chain surgery and R10 deep
// prefetch each moved it only slightly. Keeps: 5-chunk-deep rotating prefetch
// (50 outstanding loads < vmcnt limit), lm for c+1 computed during c
// (off-chain), renorm every 2nd chunk with the skipped max folded into the
// next log2 exactly.
__global__ __launch_bounds__(64)
void crf_phase2(const float* __restrict__ em,
                const float* __restrict__ strt,
                const float* __restrict__ endt,
                const int*   __restrict__ tags,
                const float* __restrict__ ws,
                float* __restrict__ out)
{
  const int tid  = threadIdx.x;
  const int lane = tid & 63;
  const int gt = (blockIdx.x << 6) + tid;
  const int b = gt >> 3;                   // batch
  const int j = gt & 7;                    // alpha row
  const int gbase = lane & 56;             // first lane of this batch's group

  const unsigned poff = ((unsigned)(j >> 1) << 12) + (unsigned)(j & 1) + ((unsigned)b << 1);
  const float* wsf = ws;

  const float al = strt[j] + em[(size_t)b * 16384u + (unsigned)j];
  const int s0 = tags[(size_t)b * 2048u] - 1;       // t=0 always valid
  float num = __shfl(al, gbase + s0, 64);           // strt[s0] + em0[s0]

  float mx = al;
  mx = fmaxf(mx, __shfl_xor(mx, 1, 64));
  mx = fmaxf(mx, __shfl_xor(mx, 2, 64));
  mx = fmaxf(mx, __shfl_xor(mx, 4, 64));
  float a = fexp2((al - mx) * LOG2E);
  float lZ2 = mx * LOG2E;

  float Pb[6][8], lsb[6], nmb[6];
  auto loadChunk = [&](int c, int s){
    const float* base = wsf + (size_t)c * 163840u;
#pragma unroll
    for (int i = 0; i < 8; ++i) Pb[s][i] = base[poff + (unsigned)i * 16384u];
    lsb[s] = base[131072u + poff];
    nmb[s] = base[147456u + ((unsigned)b << 1)];
  };

  loadChunk(0, 0); loadChunk(1, 1); loadChunk(2, 2);
  loadChunk(3, 3); loadChunk(4, 4);

  float lm_next;
  {
    float t0 = lsb[0];
    t0 = fmaxf(t0, __shfl_xor(t0, 1, 64));
    t0 = fmaxf(t0, __shfl_xor(t0, 2, 64));
    t0 = fmaxf(t0, __shfl_xor(t0, 4, 64));
    lm_next = t0;
  }

#pragma unroll
  for (int c = 0; c < 8; ++c){
    const int s = c % 6;                   // static under full unroll (8 iters)
    if (c + 5 < 8) loadChunk(c + 5, (c + 5) % 6);

    const float lm = lm_next;
    const float w = a * fexp2(lsb[s] - lm);

    // next chunk's lm: depends only on prefetched lsb -> overlaps acc chain
    if (c + 1 < 8){
      float t1 = lsb[(c + 1) % 6];
      t1 = fmaxf(t1, __shfl_xor(t1, 1, 64));
      t1 = fmaxf(t1, __shfl_xor(t1, 2, 64));
      t1 = fmaxf(t1, __shfl_xor(t1, 4, 64));
      lm_next = t1;
    }

    // alpha'[j] = sum_i w_i * P[col i][row j]
    float acc = 0.f;
#pragma unroll
    for (int i = 0; i < 8; ++i)
      acc += __shfl(w, gbase + i, 64) * Pb[s][i];

    lZ2 += lm;
    if (c & 1){                            // renorm every 2nd chunk (exact)
      float m2 = acc;
      m2 = fmaxf(m2, __shfl_xor(m2, 1, 64));
      m2 = fmaxf(m2, __shfl_xor(m2, 2, 64));
      m2 = fmaxf(m2, __shfl_xor(m2, 4, 64));
      a = acc * __builtin_amdgcn_rcpf(m2);
      lZ2 += flog2(m2);
    } else {
      a = acc;                             // bounded; folded into next log2
    }
    num += nmb[s];
  }

  // denominator (c=7 is odd -> a is renormalized here)
  float t = a * fexp2(endt[j] * LOG2E);
  t += __shfl_xor(t, 1, 64);
  t += __shfl_xor(t, 2, 64);
  t += __shfl_xor(t, 4, 64);
  const float denom = (flog2(t) + lZ2) * LN2;

  float contrib = (j == 0) ? (denom - num) * (1.0f / 2048.0f) : 0.f;
  contrib += __shfl_xor(contrib, 8, 64);
  contrib += __shfl_xor(contrib, 16, 64);
  contrib += __shfl_xor(contrib, 32, 64);
  if (lane == 0) atomicAdd(out, contrib);
}

extern "C" void kernel_launch(void* const* d_in, const int* in_sizes, int n_in,
                              void* d_out, int out_size, void* d_ws, size_t ws_size,
                              hipStream_t stream) {
  const float* em    = (const float*)d_in[0];
  const float* trans = (const float*)d_in[1];
  const float* strt  = (const float*)d_in[2];
  const float* endt  = (const float*)d_in[3];
  const int*   tags  = (const int*)d_in[4];
  float* out = (float*)d_out;

  // out is zeroed by crf_phase1 block 0 (stream order precedes phase2 atomics)
  // C=8 chunks of S=256 steps; 16384 (b,c) pairs, 4 per wave -> 1024 blocks of 256
  crf_phase1<<<1024, 256, 0, stream>>>(em, trans, endt, tags, (float*)d_ws, out);
  // 256 one-wave blocks: one scan-wave per CU; 8-iteration serial combine
  crf_phase2<<<256, 64, 0, stream>>>(em, strt, endt, tags, (const float*)d_ws, out);
}

// Round 8
// 243.992 us; speedup vs baseline: 1.0211x; 1.0211x over previous
//
#include <hip/hip_runtime.h>
#include <stdint.h>

typedef float  v4f __attribute__((ext_vector_type(4)));
typedef short  v4s __attribute__((ext_vector_type(4)));

#define LOG2E 1.44269504088896340736f
#define LN2   0.69314718055994530942f

static __device__ __forceinline__ float fexp2(float x){ return __builtin_amdgcn_exp2f(x); }
static __device__ __forceinline__ float flog2(float x){ return __builtin_amdgcn_logf(x); }

// pack two f32 -> two bf16 (round-half-up) in one dword via v_perm — PROVEN in R1-R4.
// (R5's __builtin_amdgcn_cvt_pk_bf16_f32 produced NaN output; suspected bad lowering.)
static __device__ __forceinline__ unsigned pkbf(float a, float b){
  unsigned ua = __float_as_uint(a) + 0x8000u;
  unsigned ub = __float_as_uint(b) + 0x8000u;
  return __builtin_amdgcn_perm(ub, ua, 0x07060302u);
}
static __device__ __forceinline__ v4s pack4(const v4f& m){
  union { unsigned u[2]; v4s s; } t;
  t.u[0] = pkbf(m.x, m.y);
  t.u[1] = pkbf(m.z, m.w);
  return t.s;
}

static __device__ __forceinline__ v4f mfma16(v4s a, v4s b, v4f c){
#if __has_builtin(__builtin_amdgcn_mfma_f32_16x16x16bf16_1k)
  return __builtin_amdgcn_mfma_f32_16x16x16bf16_1k(a, b, c, 0, 0, 0);
#else
  v4f r = c;
  asm("s_nop 1\n\tv_mfma_f32_16x16x16_bf16 %0, %1, %2, %0\n\ts_nop 7\n\ts_nop 1"
      : "+v"(r) : "v"(a), "v"(b));
  return r;
#endif
}

static __device__ __forceinline__ float sel4(const v4f& e4, int s){
  float a = (s & 1) ? e4.y : e4.x;
  float c = (s & 1) ? e4.w : e4.z;
  return (s & 2) ? c : a;
}

// ---------------- Phase 1 ----------------
// Geometry: C=32 chunks of S=64 (R11's C=8 regressed: exactly-filling grid
// exposed tail imbalance, phase1 80->92.5us).
// One MFMA = 4 (batch,chunk) 8x8 transfer-matrix products (blockdiag(E^T,E^T),
// 2x2 column-octets). Lane roles: n=lane&15, q=lane>>4, qr=q&1 (r0=4*qr),
// cn=n&7, matrix mm=((q>>1)<<1)|(n>>3). P' = diag(exp(em_t)) * E^T * P.
// D (C-layout) == next B (B-layout) -> zero-shuffle feedback.
// R12: phase1 is stall-dominated (VALUBusy 40%, MfmaUtil 7%, chain model
// ~4x faster than measured). Unmasked region (c<=15) runs TWO independent
// chains per wave (chunks 2k,2k+1 of one batch) to double schedulable work
// at stall sites. Unlike R9 (regressed), e-broadcasts stay as the PROVEN
// bulk per-kb e8[8] LDS reads for both chains — R9's regression was its
// short-lead rotating reads exposing lgkmcnt, not dual-chain itself.
// Masked region (c>=16) keeps the proven single-chain path (per-kb ballot
// mask byte, wave-uniform triage, MFMA always full-EXEC, dead-break).

__device__ __forceinline__ void renorm(v4f& master, v4s& bfrag, float& lZ){
  float mx = fmaxf(fmaxf(master.x, master.y), fmaxf(master.z, master.w));
  mx = fmaxf(mx, __shfl_xor(mx, 16, 64));
  const float inv = __builtin_amdgcn_rcpf(mx);
  master.x *= inv; master.y *= inv; master.z *= inv; master.w *= inv;
  lZ += flog2(mx);
  bfrag = pack4(master);
}

// ---- dual-chain, unmasked-only (R9-proven control flow + R7-proven e8) ----
__device__ __forceinline__ void chunk_loop_dual(
    const float* __restrict__ embA, const int* __restrict__ tgbA, bool c0A,
    const float* __restrict__ embB, const int* __restrict__ tgbB,
    const float* s_trans, float* s_slotA, float* s_slotB,
    v4s afrag, int qr, int cn,
    v4f& mA, v4s& bA, float& lZA, float& numA,
    v4f& mB, v4s& bB, float& lZB, float& numB)
{
  v4f eoA[3], eoB[3]; int tcA[3], tpA[3], tcB[3], tpB[3];

  auto loadA = [&](int kb, int buf){
    const int t0 = kb << 3;
    eoA[buf] = *(const v4f*)(embA + (size_t)(t0 + cn) * 8u);
    tcA[buf] = tgbA[t0 + cn];
    int ip = t0 + cn - 1;
    if (c0A && ip < 0) ip = 0;           // global t=0: value unused
    tpA[buf] = tgbA[ip];
  };
  auto loadB = [&](int kb, int buf){
    const int t0 = kb << 3;
    eoB[buf] = *(const v4f*)(embB + (size_t)(t0 + cn) * 8u);
    tcB[buf] = tgbB[t0 + cn];
    tpB[buf] = tgbB[t0 + cn - 1];        // cB>=1 always: index >= 63
  };
  auto expwA = [&](const v4f& e, int par){
    v4f ed;
    ed.x = fexp2(e.x * LOG2E); ed.y = fexp2(e.y * LOG2E);
    ed.z = fexp2(e.z * LOG2E); ed.w = fexp2(e.w * LOG2E);
    *(v4f*)(s_slotA + (par << 5) + (cn << 2)) = ed;
  };
  auto expwB = [&](const v4f& e, int par){
    v4f ed;
    ed.x = fexp2(e.x * LOG2E); ed.y = fexp2(e.y * LOG2E);
    ed.z = fexp2(e.z * LOG2E); ed.w = fexp2(e.w * LOG2E);
    *(v4f*)(s_slotB + (par << 5) + (cn << 2)) = ed;
  };

  loadA(0, 0); loadB(0, 0);
  loadA(1, 1); loadB(1, 1);
  loadA(2, 2); loadB(2, 2);
  expwA(eoA[0], 0); expwB(eoB[0], 0);

#pragma unroll
  for (int kb = 0; kb < 8; ++kb){
    const int buf = kb % 3;
    const bool skA = c0A && (kb == 0);   // wave-uniform

    // distributed numerators for step t = kb*8 + cn (unmasked: always active)
    {
      const bool act = !(skA && cn == 0);
      const int s = tcA[buf] - 1;
      const float ev = sel4(eoA[buf], s);
      numA += (act && ((s >> 2) == qr)) ? ev : 0.f;
      const float tv = s_trans[(((tpA[buf] - 1) & 7) << 3) + (s & 7)];
      numA += (act && (qr == 0)) ? tv : 0.f;
    }
    {
      const int s = tcB[buf] - 1;
      const float ev = sel4(eoB[buf], s);
      numB += ((s >> 2) == qr) ? ev : 0.f;
      const float tv = s_trans[(((tpB[buf] - 1) & 7) << 3) + (s & 7)];
      numB += (qr == 0) ? tv : 0.f;
    }

    // bulk broadcast exps for this kb (written one full kb ago) — R7 style
    v4f e8A[8], e8B[8];
    const float* slA = s_slotA + ((kb & 1) << 5);
    const float* slB = s_slotB + ((kb & 1) << 5);
#pragma unroll
    for (int j = 0; j < 8; ++j){
      e8A[j] = *(const v4f*)(slA + (j << 2));
      e8B[j] = *(const v4f*)(slB + (j << 2));
    }

    // exps for next kb -> other parity slot; deep prefetch of kb+3 em/tags
    if (kb + 1 < 8){ expwA(eoA[(kb + 1) % 3], (kb + 1) & 1);
                     expwB(eoB[(kb + 1) % 3], (kb + 1) & 1); }
    if (kb + 3 < 8){ loadA(kb + 3, buf); loadB(kb + 3, buf); }

    // 8 recurrence steps, chains interleaved (independent -> ILP)
#pragma unroll
    for (int j = 0; j < 8; ++j){
      v4f zero = {0.f, 0.f, 0.f, 0.f};
      if (!(skA && j == 0)){             // wave-uniform: global t=0 in phase 2
        v4f d = mfma16(afrag, bA, zero);
        const v4f e = e8A[j];
        mA.x = d.x * e.x; mA.y = d.y * e.y;
        mA.z = d.z * e.z; mA.w = d.w * e.w;
        bA = pack4(mA);
      }
      {
        v4f d = mfma16(afrag, bB, zero);
        const v4f e = e8B[j];
        mB.x = d.x * e.x; mB.y = d.y * e.y;
        mB.z = d.z * e.z; mB.w = d.w * e.w;
        bB = pack4(mB);
      }
    }

    if (kb & 1){                          // renorm every 16 steps, per chain
      renorm(mA, bA, lZA);
      renorm(mB, bB, lZB);
    }
  }
}

// ---- single-chain masked (R7-proven) ----
template<bool MASKED>
__device__ __forceinline__ void chunk_loop(
    const float* __restrict__ emb, const int* __restrict__ tgb, int c,
    const float* s_trans, const float* s_end, float* s_slot,
    v4s afrag, int qr, int r0, int cn, bool lastChunk,
    v4f& master, v4s& bfrag, float& lZ, float& num)
{
  v4f eo[3]; int tc[3], tp[3];

  auto loadK = [&](int kb, int buf){
    const int t0 = kb << 3;
    eo[buf] = *(const v4f*)(emb + (size_t)(t0 + cn) * 8u);
    tc[buf] = tgb[t0 + cn];
    int ip = t0 + cn - 1;
    if (c == 0 && ip < 0) ip = 0;
    tp[buf] = tgb[ip];
  };

  auto expwrite = [&](const v4f& e, int par){
    v4f ed;
    ed.x = fexp2(e.x * LOG2E); ed.y = fexp2(e.y * LOG2E);
    ed.z = fexp2(e.z * LOG2E); ed.w = fexp2(e.w * LOG2E);
    *(v4f*)(s_slot + (par << 5) + (cn << 2)) = ed;
  };

  loadK(0, 0); loadK(1, 1); loadK(2, 2);
  expwrite(eo[0], 0);

#pragma unroll
  for (int kb = 0; kb < 8; ++kb){
    const int buf = kb % 3;

    const bool sk0 = (!MASKED) && (c == 0) && (kb == 0);
    {
      bool act = MASKED ? (tc[buf] != 0) : true;
      if (sk0 && cn == 0) act = false;
      const int s = tc[buf] - 1;
      const float ev = sel4(eo[buf], s);
      num += (act && ((s >> 2) == qr)) ? ev : 0.f;
      const float tv = s_trans[(((tp[buf] - 1) & 7) << 3) + (s & 7)];
      num += (act && (qr == 0)) ? tv : 0.f;
      if (MASKED && (tp[buf] != 0) && (tc[buf] == 0) && (qr == 0))
        num += s_end[tp[buf] - 1];
    }

    unsigned mb = 0xffu;
    bool allAlive = true;                 // wave-uniform
    if (MASKED){
      const unsigned long long bal = __ballot(tc[buf] != 0);
      if (bal == 0ull) break;             // wave-uniform: all 4 matrices dead
      mb = (unsigned)(bal >> (threadIdx.x & 56)) & 0xffu;
      allAlive = (bal == ~0ull);
    }

    v4f e8[8];
    const float* sl = s_slot + ((kb & 1) << 5);
#pragma unroll
    for (int j = 0; j < 8; ++j) e8[j] = *(const v4f*)(sl + (j << 2));

    if (kb + 1 < 8) expwrite(eo[(kb + 1) % 3], (kb + 1) & 1);
    if (kb + 3 < 8) loadK(kb + 3, buf);

    if (!MASKED || allAlive){
#pragma unroll
      for (int j = 0; j < 8; ++j){
        if (sk0 && j == 0) continue;
        v4f zero = {0.f, 0.f, 0.f, 0.f};
        v4f d = mfma16(afrag, bfrag, zero);
        const v4f e = e8[j];
        master.x = d.x * e.x; master.y = d.y * e.y;
        master.z = d.z * e.z; master.w = d.w * e.w;
        bfrag = pack4(master);
      }
    } else {
#pragma unroll
      for (int j = 0; j < 8; ++j){
        v4f zero = {0.f, 0.f, 0.f, 0.f};
        v4f d = mfma16(afrag, bfrag, zero);
        const v4f e = e8[j];
        const bool v = (mb >> j) & 1u;   // per-lane cndmask, no branch
        master.x = v ? d.x * e.x : master.x;
        master.y = v ? d.y * e.y : master.y;
        master.z = v ? d.z * e.z : master.z;
        master.w = v ? d.w * e.w : master.w;
        bfrag = pack4(master);
      }
    }

    if (kb & 1) renorm(master, bfrag, lZ);
  }

  if (MASKED && lastChunk){
    const int lt = tgb[63];               // tag at global t = L-1
    if ((lt != 0) && (qr == 0) && (cn == 0)) num += s_end[lt - 1];
  }
}

__global__ __launch_bounds__(256, 4)
void crf_phase1(const float* __restrict__ em,
                const float* __restrict__ trans,
                const float* __restrict__ endt,
                const int*   __restrict__ tags,
                float* __restrict__ ws,
                float* __restrict__ out)
{
  const int tid  = threadIdx.x;
  const int lane = tid & 63;
  const int n = lane & 15, q = lane >> 4, qr = q & 1, r0 = qr << 2, cn = n & 7;
  const int mm = ((q >> 1) << 1) | (n >> 3);

  if (blockIdx.x == 0 && tid == 0) out[0] = 0.f;   // replaces memset dispatch

  __shared__ float s_trans[64];
  __shared__ float s_end[8];
  __shared__ float s_e[2 * 32 * 68];      // 32 groups x 2 chains x (2x32+4 pad)
  if (tid < 64) s_trans[tid] = trans[tid];
  if (tid < 8)  s_end[tid]  = endt[tid];
  __syncthreads();

  // constant A fragment: blockdiag(E^T, E^T); A[m][k], m=n, k=4q+j
  v4s afrag;
  {
    float av[4];
#pragma unroll
    for (int j = 0; j < 4; ++j){
      const int k = (q << 2) + j;
      float v = 0.f;
      if (n < 8 && k < 8)        v = fexp2(s_trans[k * 8 + n] * LOG2E);
      else if (n >= 8 && k >= 8) v = fexp2(s_trans[(k - 8) * 8 + (n - 8)] * LOG2E);
      av[j] = v;
    }
    union { unsigned u[2]; v4s s; } t;
    t.u[0] = pkbf(av[0], av[1]);
    t.u[1] = pkbf(av[2], av[3]);
    afrag = t.s;
  }

  float* s_slotA = &s_e[(tid >> 3) * 68];
  float* s_slotB = s_slotA + 32 * 68;

  auto ident = [&](v4f& m){
    m.x = (r0 + 0 == cn) ? 1.f : 0.f;
    m.y = (r0 + 1 == cn) ? 1.f : 0.f;
    m.z = (r0 + 2 == cn) ? 1.f : 0.f;
    m.w = (r0 + 3 == cn) ? 1.f : 0.f;
  };

  auto store = [&](int c, int bm, const v4f& master, float lZ, float num){
    float2* ws2 = ((float2*)ws) + (size_t)c * 40u * 2048u + (unsigned)bm;
    const int e0 = (cn << 3) + r0;         // entry e = col*8 + row (even)
    float2 v01; v01.x = master.x; v01.y = master.y;
    float2 v23; v23.x = master.z; v23.y = master.w;
    ws2[(size_t)(e0 >> 1) * 2048u]       = v01;
    ws2[(size_t)((e0 >> 1) + 1) * 2048u] = v23;
    if (qr == 0)
      ((float*)(ws2 + (size_t)((64 + cn) >> 1) * 2048u))[cn & 1] = lZ;
    float nm = num;
    nm += __shfl_xor(nm, 1, 64);
    nm += __shfl_xor(nm, 2, 64);
    nm += __shfl_xor(nm, 4, 64);
    nm += __shfl_xor(nm, 16, 64);
    if (qr == 0 && cn == 0)
      ((float*)(ws2 + (size_t)36 * 2048u))[0] = nm;
  };

  if (blockIdx.x < 1024){
    // ---- unmasked dual-chain region: chunks (2k, 2k+1), c <= 15 ----
    const int u  = (blockIdx.x << 4) + ((tid >> 6) << 2) + mm;
    const int bm = u & 2047;
    const int cp = u >> 11;                // chunk pair 0..7
    const int cA = cp << 1, cB = cA + 1;

    const float* embA = em + ((size_t)bm * 2048u + (size_t)cA * 64u) * 8u + (unsigned)r0;
    const float* embB = em + ((size_t)bm * 2048u + (size_t)cB * 64u) * 8u + (unsigned)r0;
    const int* tgbA = tags + (size_t)bm * 2048u + (size_t)cA * 64u;
    const int* tgbB = tags + (size_t)bm * 2048u + (size_t)cB * 64u;

    v4f mA, mB; ident(mA); ident(mB);
    v4s bA = pack4(mA), bB = pack4(mB);
    float numA = 0.f, lZA = 0.f, numB = 0.f, lZB = 0.f;

    chunk_loop_dual(embA, tgbA, (cp == 0), embB, tgbB,
                    s_trans, s_slotA, s_slotB, afrag, qr, cn,
                    mA, bA, lZA, numA, mB, bB, lZB, numB);

    store(cA, bm, mA, lZA, numA);
    store(cB, bm, mB, lZB, numB);
  } else {
    // ---- masked single-chain region: c >= 16 ----
    const int p  = 32768 + ((blockIdx.x - 1024) << 4) + ((tid >> 6) << 2) + mm;
    const int c  = p >> 11;                // 16..31
    const int bm = p & 2047;

    const float* emb = em   + ((size_t)bm * 2048u + (size_t)c * 64u) * 8u + (unsigned)r0;
    const int*   tgb = tags + (size_t)bm * 2048u + (size_t)c * 64u;

    v4f master; ident(master);
    v4s bfrag = pack4(master);
    float num = 0.f, lZ = 0.f;

    const bool fz = (tgb[0] == 0);
    if (__ballot(fz) == ~0ull){            // all 4 pairs fully masked: identity
      const int pv = tgb[-1];
      if ((pv != 0) && (qr == 0) && (cn == 0)) num = s_end[pv - 1];
    } else {
      chunk_loop<true>(emb, tgb, c, s_trans, s_end, s_slotA,
                       afrag, qr, r0, cn, (c == 31), master, bfrag, lZ, num);
    }
    store(c, bm, master, lZ, num);
  }
}

// ---------------- Phase 2: per-batch combine of chunk matrices ----------------
// R10 version verbatim (proven): 8 lanes per batch; 256 one-wave blocks;
// 5-chunk-deep rotating prefetch (50 outstanding loads < vmcnt limit);
// lm for c+1 computed during c (off-chain); renorm every 2nd chunk with the
// skipped max folded into the next log2 exactly.
__global__ __launch_bounds__(64)
void crf_phase2(const float* __restrict__ em,
                const float* __restrict__ strt,
                const float* __restrict__ endt,
                const int*   __restrict__ tags,
                const float* __restrict__ ws,
                float* __restrict__ out)
{
  const int tid  = threadIdx.x;
  const int lane = tid & 63;
  const int gt = (blockIdx.x << 6) + tid;
  const int b = gt >> 3;                   // batch
  const int j = gt & 7;                    // alpha row
  const int gbase = lane & 56;             // first lane of this batch's group

  const unsigned poff = ((unsigned)(j >> 1) << 12) + (unsigned)(j & 1) + ((unsigned)b << 1);
  const float* wsf = ws;

  const float al = strt[j] + em[(size_t)b * 16384u + (unsigned)j];
  const int s0 = tags[(size_t)b * 2048u] - 1;       // t=0 always valid
  float num = __shfl(al, gbase + s0, 64);           // strt[s0] + em0[s0]

  float mx = al;
  mx = fmaxf(mx, __shfl_xor(mx, 1, 64));
  mx = fmaxf(mx, __shfl_xor(mx, 2, 64));
  mx = fmaxf(mx, __shfl_xor(mx, 4, 64));
  float a = fexp2((al - mx) * LOG2E);
  float lZ2 = mx * LOG2E;

  float Pb[6][8], lsb[6], nmb[6];
  auto loadChunk = [&](int c, int s){
    const float* base = wsf + (size_t)c * 163840u;
#pragma unroll
    for (int i = 0; i < 8; ++i) Pb[s][i] = base[poff + (unsigned)i * 16384u];
    lsb[s] = base[131072u + poff];
    nmb[s] = base[147456u + ((unsigned)b << 1)];
  };

  loadChunk(0, 0); loadChunk(1, 1); loadChunk(2, 2);
  loadChunk(3, 3); loadChunk(4, 4);

  float lm_next;
  {
    float t0 = lsb[0];
    t0 = fmaxf(t0, __shfl_xor(t0, 1, 64));
    t0 = fmaxf(t0, __shfl_xor(t0, 2, 64));
    t0 = fmaxf(t0, __shfl_xor(t0, 4, 64));
    lm_next = t0;
  }

#pragma unroll
  for (int c = 0; c < 32; ++c){
    const int s = c % 6;                   // static under full unroll
    if (c + 5 < 32) loadChunk(c + 5, (c + 5) % 6);

    const float lm = lm_next;
    const float w = a * fexp2(lsb[s] - lm);

    // next chunk's lm: depends only on prefetched lsb -> overlaps acc chain
    if (c + 1 < 32){
      float t1 = lsb[(c + 1) % 6];
      t1 = fmaxf(t1, __shfl_xor(t1, 1, 64));
      t1 = fmaxf(t1, __shfl_xor(t1, 2, 64));
      t1 = fmaxf(t1, __shfl_xor(t1, 4, 64));
      lm_next = t1;
    }

    // alpha'[j] = sum_i w_i * P[col i][row j]
    float acc = 0.f;
#pragma unroll
    for (int i = 0; i < 8; ++i)
      acc += __shfl(w, gbase + i, 64) * Pb[s][i];

    lZ2 += lm;
    if (c & 1){                            // renorm every 2nd chunk (exact)
      float m2 = acc;
      m2 = fmaxf(m2, __shfl_xor(m2, 1, 64));
      m2 = fmaxf(m2, __shfl_xor(m2, 2, 64));
      m2 = fmaxf(m2, __shfl_xor(m2, 4, 64));
      a = acc * __builtin_amdgcn_rcpf(m2);
      lZ2 += flog2(m2);
    } else {
      a = acc;                             // bounded; folded into next log2
    }
    num += nmb[s];
  }

  float t = a * fexp2(endt[j] * LOG2E);
  t += __shfl_xor(t, 1, 64);
  t += __shfl_xor(t, 2, 64);
  t += __shfl_xor(t, 4, 64);
  const float denom = (flog2(t) + lZ2) * LN2;

  float contrib = (j == 0) ? (denom - num) * (1.0f / 2048.0f) : 0.f;
  contrib += __shfl_xor(contrib, 8, 64);
  contrib += __shfl_xor(contrib, 16, 64);
  contrib += __shfl_xor(contrib, 32, 64);
  if (lane == 0) atomicAdd(out, contrib);
}

extern "C" void kernel_launch(void* const* d_in, const int* in_sizes, int n_in,
                              void* d_out, int out_size, void* d_ws, size_t ws_size,
                              hipStream_t stream) {
  const float* em    = (const float*)d_in[0];
  const float* trans = (const float*)d_in[1];
  const float* strt  = (const float*)d_in[2];
  const float* endt  = (const float*)d_in[3];
  const int*   tags  = (const int*)d_in[4];
  float* out = (float*)d_out;

  // out is zeroed by crf_phase1 block 0 (stream order precedes phase2 atomics)
  // blocks 0..1023: dual-chain unmasked (c 0..15); 1024..3071: masked (c 16..31)
  crf_phase1<<<3072, 256, 0, stream>>>(em, trans, endt, tags, (float*)d_ws, out);
  // 256 one-wave blocks: one scan-wave per CU; 32-iteration serial combine
  crf_phase2<<<256, 64, 0, stream>>>(em, strt, endt, tags, (const float*)d_ws, out);
}

// Round 10
// 235.971 us; speedup vs baseline: 1.0558x; 1.0340x over previous
//
#include <hip/hip_runtime.h>
#include <stdint.h>

typedef float  v4f __attribute__((ext_vector_type(4)));
typedef short  v4s __attribute__((ext_vector_type(4)));

#define LOG2E 1.44269504088896340736f
#define LN2   0.69314718055994530942f

static __device__ __forceinline__ float fexp2(float x){ return __builtin_amdgcn_exp2f(x); }
static __device__ __forceinline__ float flog2(float x){ return __builtin_amdgcn_logf(x); }

// pack two f32 -> two bf16 (round-half-up) via v_perm — PROVEN in R1-R4.
// Kept for afrag init (off hot path; reused every step so keep the rounding).
static __device__ __forceinline__ unsigned pkbf(float a, float b){
  unsigned ua = __float_as_uint(a) + 0x8000u;
  unsigned ub = __float_as_uint(b) + 0x8000u;
  return __builtin_amdgcn_perm(ub, ua, 0x07060302u);
}

// R14 hot-path pack: TRUNCATING bf16 pack, 1 v_perm per pair (2 ops/step vs 6).
// Phase1 is issue-bound (R12 PM); this is the same 4-VALU/step cut cvt_pk
// promised, via the proven perm path. (v_cvt_pk_bf16_f32 NaN'd through BOTH
// builtin (R5) and inline asm (R13) — permanently off the table.)
// Numerics: post-renorm P entries in [0,1]; truncation bias < 1 bf16 ulp/step,
// compounding to ~4 absolute on the final NLL (output ulp 8-16, threshold 77).
static __device__ __forceinline__ v4s pack4(const v4f& m){
  union { unsigned u[2]; v4s s; } t;
  t.u[0] = __builtin_amdgcn_perm(__float_as_uint(m.y), __float_as_uint(m.x), 0x07060302u);
  t.u[1] = __builtin_amdgcn_perm(__float_as_uint(m.w), __float_as_uint(m.z), 0x07060302u);
  return t.s;
}

static __device__ __forceinline__ v4f mfma16(v4s a, v4s b, v4f c){
#if __has_builtin(__builtin_amdgcn_mfma_f32_16x16x16bf16_1k)
  return __builtin_amdgcn_mfma_f32_16x16x16bf16_1k(a, b, c, 0, 0, 0);
#else
  v4f r = c;
  asm("s_nop 1\n\tv_mfma_f32_16x16x16_bf16 %0, %1, %2, %0\n\ts_nop 7\n\ts_nop 1"
      : "+v"(r) : "v"(a), "v"(b));
  return r;
#endif
}

static __device__ __forceinline__ float sel4(const v4f& e4, int s){
  float a = (s & 1) ? e4.y : e4.x;
  float c = (s & 1) ? e4.w : e4.z;
  return (s & 2) ? c : a;
}

// ---------------- Phase 1 ----------------
// EXACT R7 structure (proven 80us, 44 VGPR, no spill) + truncating pack4.
// One chain per wave: 4 (batch,chunk) 8x8 transfer-matrix products via one
// 16x16x16 bf16 MFMA (blockdiag(E^T,E^T), 2x2 column-octets).
// Lane roles: n=lane&15, q=lane>>4, qr=q&1 (row half r0=4*qr), cn=n&7 (column),
// matrix mm=((q>>1)<<1)|(n>>3). Recurrence P' = diag(exp(em_t)) * E^T * P.
// D (C-layout) == next B (B-layout) -> zero-shuffle feedback.
// Pipelining: em/tags prefetched 2 blocks ahead (3 buffers); exps for block kb+1
// computed+written to the LDS broadcast slot during block kb. Per-wave DS ops
// are in-order: no barrier. Masks from one per-kb __ballot (tags monotone);
// wave-uniform triage (MFMA always full-EXEC); masked body is cndmask.
// MODEL (R12 post-mortem): phase1 is ISSUE-BOUND (~39k issue cyc/SIMD vs 48k
// measured; dep-chain model only 15k). R8 occupancy -> spill; R9/R12 dual-chain
// ADD instructions -> slower. Only instruction-count cuts help.

template<bool MASKED>
__device__ __forceinline__ void chunk_loop(
    const float* __restrict__ emb, const int* __restrict__ tgb, int c,
    const float* s_trans, const float* s_end, float* s_slot,
    v4s afrag, int qr, int r0, int cn, bool lastChunk,
    v4f& master, v4s& bfrag, float& lZ, float& num)
{
  v4f eo[3]; int tc[3], tp[3];

  auto loadK = [&](int kb, int buf){
    const int t0 = kb << 3;
    eo[buf] = *(const v4f*)(emb + (size_t)(t0 + cn) * 8u);
    tc[buf] = tgb[t0 + cn];
    int ip = t0 + cn - 1;
    if (c == 0 && ip < 0) ip = 0;        // global t=0: value unused
    tp[buf] = tgb[ip];
  };

  auto expwrite = [&](const v4f& e, int par){
    v4f ed;
    ed.x = fexp2(e.x * LOG2E); ed.y = fexp2(e.y * LOG2E);
    ed.z = fexp2(e.z * LOG2E); ed.w = fexp2(e.w * LOG2E);
    *(v4f*)(s_slot + (par << 5) + (cn << 2)) = ed;   // ds_write_b128
  };

  loadK(0, 0); loadK(1, 1); loadK(2, 2);
  expwrite(eo[0], 0);

#pragma unroll
  for (int kb = 0; kb < 8; ++kb){
    const int buf = kb % 3;

    // distributed numerator for step t = kb*8 + cn (must precede dead-break:
    // the end_transitions add fires on the first masked step of the batch)
    const bool sk0 = (!MASKED) && (c == 0) && (kb == 0);
    {
      bool act = MASKED ? (tc[buf] != 0) : true;
      if (sk0 && cn == 0) act = false;
      const int s = tc[buf] - 1;
      const float ev = sel4(eo[buf], s);
      num += (act && ((s >> 2) == qr)) ? ev : 0.f;
      const float tv = s_trans[(((tp[buf] - 1) & 7) << 3) + (s & 7)];
      num += (act && (qr == 0)) ? tv : 0.f;
      if (MASKED && (tp[buf] != 0) && (tc[buf] == 0) && (qr == 0))
        num += s_end[tp[buf] - 1];
    }

    // per-kb mask byte from one ballot; tags are monotone -> all-zero kb
    // means every later step is masked too: stop the chunk. Both octets of a
    // matrix see identical bytes, so mb is coherent per matrix.
    unsigned mb = 0xffu;
    bool allAlive = true;                 // wave-uniform
    if (MASKED){
      const unsigned long long bal = __ballot(tc[buf] != 0);
      if (bal == 0ull) break;             // wave-uniform: all 4 matrices dead
      mb = (unsigned)(bal >> (threadIdx.x & 56)) & 0xffu;
      allAlive = (bal == ~0ull);
    }

    // broadcast exps for this block (written one block ago)
    v4f e8[8];
    const float* sl = s_slot + ((kb & 1) << 5);
#pragma unroll
    for (int j = 0; j < 8; ++j) e8[j] = *(const v4f*)(sl + (j << 2));

    // exps for next block -> other parity slot (distance = one full block)
    if (kb + 1 < 8) expwrite(eo[(kb + 1) % 3], (kb + 1) & 1);
    if (kb + 3 < 8) loadK(kb + 3, buf);

    // 8 recurrence steps — branch is wave-uniform; MFMA always full-EXEC
    if (!MASKED || allAlive){
#pragma unroll
      for (int j = 0; j < 8; ++j){
        if (sk0 && j == 0) continue;     // global t=0 handled in phase 2
        v4f zero = {0.f, 0.f, 0.f, 0.f};
        v4f d = mfma16(afrag, bfrag, zero);
        const v4f e = e8[j];
        master.x = d.x * e.x; master.y = d.y * e.y;
        master.z = d.z * e.z; master.w = d.w * e.w;
        bfrag = pack4(master);
      }
    } else {
#pragma unroll
      for (int j = 0; j < 8; ++j){
        v4f zero = {0.f, 0.f, 0.f, 0.f};
        v4f d = mfma16(afrag, bfrag, zero);
        const v4f e = e8[j];
        const bool v = (mb >> j) & 1u;   // per-lane cndmask, no branch
        master.x = v ? d.x * e.x : master.x;
        master.y = v ? d.y * e.y : master.y;
        master.z = v ? d.z * e.z : master.z;
        master.w = v ? d.w * e.w : master.w;
        bfrag = pack4(master);
      }
    }

    if (kb & 1){                          // renorm every 16 steps
      float mx = fmaxf(fmaxf(master.x, master.y), fmaxf(master.z, master.w));
      mx = fmaxf(mx, __shfl_xor(mx, 16, 64));
      const float inv = __builtin_amdgcn_rcpf(mx);
      master.x *= inv; master.y *= inv; master.z *= inv; master.w *= inv;
      lZ += flog2(mx);
      bfrag = pack4(master);
    }
  }

  if (MASKED && lastChunk){
    const int lt = tgb[63];               // tag at global t = L-1
    if ((lt != 0) && (qr == 0) && (cn == 0)) num += s_end[lt - 1];
  }
}

__global__ __launch_bounds__(256, 4)
void crf_phase1(const float* __restrict__ em,
                const float* __restrict__ trans,
                const float* __restrict__ endt,
                const int*   __restrict__ tags,
                float* __restrict__ ws,
                float* __restrict__ out)
{
  const int tid  = threadIdx.x;
  const int lane = tid & 63;
  const int n = lane & 15, q = lane >> 4, qr = q & 1, r0 = qr << 2, cn = n & 7;
  const int mm = ((q >> 1) << 1) | (n >> 3);
  const int p  = (blockIdx.x << 4) + ((tid >> 6) << 2) + mm;
  const int c  = p >> 11;                 // chunk id (S=64, C=32)
  const int bm = p & 2047;                // batch id

  if (blockIdx.x == 0 && tid == 0) out[0] = 0.f;   // replaces memset dispatch

  __shared__ float s_trans[64];
  __shared__ float s_end[8];
  __shared__ float s_e[32 * 68];          // 32 groups x (2 slots x 32 + 4 pad)
  if (tid < 64) s_trans[tid] = trans[tid];
  if (tid < 8)  s_end[tid]  = endt[tid];
  __syncthreads();

  // constant A fragment: blockdiag(E^T, E^T); A[m][k], m=n, k=4q+j
  v4s afrag;
  {
    float av[4];
#pragma unroll
    for (int j = 0; j < 4; ++j){
      const int k = (q << 2) + j;
      float v = 0.f;
      if (n < 8 && k < 8)        v = fexp2(s_trans[k * 8 + n] * LOG2E);
      else if (n >= 8 && k >= 8) v = fexp2(s_trans[(k - 8) * 8 + (n - 8)] * LOG2E);
      av[j] = v;
    }
    union { unsigned u[2]; v4s s; } t;
    t.u[0] = pkbf(av[0], av[1]);
    t.u[1] = pkbf(av[2], av[3]);
    afrag = t.s;
  }

  const float* emb = em   + ((size_t)bm * 2048u + (size_t)c * 64u) * 8u + (unsigned)r0;
  const int*   tgb = tags + (size_t)bm * 2048u + (size_t)c * 64u;
  float* s_slot = &s_e[(tid >> 3) * 68];

  // P = identity (exact in bf16; truncation pack is exact here)
  v4f master;
  master.x = (r0 + 0 == cn) ? 1.f : 0.f;
  master.y = (r0 + 1 == cn) ? 1.f : 0.f;
  master.z = (r0 + 2 == cn) ? 1.f : 0.f;
  master.w = (r0 + 3 == cn) ? 1.f : 0.f;
  v4s bfrag = pack4(master);
  float num = 0.f, lZ = 0.f;

  if (c <= 15){                            // steps < 1024: never masked
    chunk_loop<false>(emb, tgb, c, s_trans, s_end, s_slot,
                      afrag, qr, r0, cn, false, master, bfrag, lZ, num);
  } else {
    const bool fz = (tgb[0] == 0);
    if (__ballot(fz) == ~0ull){            // all 4 pairs fully masked: identity
      const int pv = tgb[-1];
      if ((pv != 0) && (qr == 0) && (cn == 0)) num = s_end[pv - 1];
    } else {
      chunk_loop<true>(emb, tgb, c, s_trans, s_end, s_slot,
                       afrag, qr, r0, cn, (c == 31), master, bfrag, lZ, num);
    }
  }

  // ---- store, [c][entry-pair][b] layout (phase-2 coalescing) ----
  float2* ws2 = ((float2*)ws) + (size_t)c * 40u * 2048u + (unsigned)bm;
  const int e0 = (cn << 3) + r0;           // entry e = col*8 + row (even)
  float2 v01; v01.x = master.x; v01.y = master.y;
  float2 v23; v23.x = master.z; v23.y = master.w;
  ws2[(size_t)(e0 >> 1) * 2048u]       = v01;
  ws2[(size_t)((e0 >> 1) + 1) * 2048u] = v23;
  if (qr == 0)
    ((float*)(ws2 + (size_t)((64 + cn) >> 1) * 2048u))[cn & 1] = lZ;
  num += __shfl_xor(num, 1, 64);
  num += __shfl_xor(num, 2, 64);
  num += __shfl_xor(num, 4, 64);
  num += __shfl_xor(num, 16, 64);
  if (qr == 0 && cn == 0)
    ((float*)(ws2 + (size_t)36 * 2048u))[0] = num;
}

// ---------------- Phase 2: per-batch combine of chunk matrices ----------------
// R10 version verbatim (proven at 235us total): 8 lanes per batch; 256
// one-wave blocks; 5-chunk-deep rotating prefetch (50 outstanding loads under
// the vmcnt limit); lm for c+1 computed during c (off-chain); renorm every
// 2nd chunk with the skipped max folded into the next log2 exactly.
__global__ __launch_bounds__(64)
void crf_phase2(const float* __restrict__ em,
                const float* __restrict__ strt,
                const float* __restrict__ endt,
                const int*   __restrict__ tags,
                const float* __restrict__ ws,
                float* __restrict__ out)
{
  const int tid  = threadIdx.x;
  const int lane = tid & 63;
  const int gt = (blockIdx.x << 6) + tid;
  const int b = gt >> 3;                   // batch
  const int j = gt & 7;                    // alpha row
  const int gbase = lane & 56;             // first lane of this batch's group

  const unsigned poff = ((unsigned)(j >> 1) << 12) + (unsigned)(j & 1) + ((unsigned)b << 1);
  const float* wsf = ws;

  const float al = strt[j] + em[(size_t)b * 16384u + (unsigned)j];
  const int s0 = tags[(size_t)b * 2048u] - 1;       // t=0 always valid
  float num = __shfl(al, gbase + s0, 64);           // strt[s0] + em0[s0]

  float mx = al;
  mx = fmaxf(mx, __shfl_xor(mx, 1, 64));
  mx = fmaxf(mx, __shfl_xor(mx, 2, 64));
  mx = fmaxf(mx, __shfl_xor(mx, 4, 64));
  float a = fexp2((al - mx) * LOG2E);
  float lZ2 = mx * LOG2E;

  float Pb[6][8], lsb[6], nmb[6];
  auto loadChunk = [&](int c, int s){
    const float* base = wsf + (size_t)c * 163840u;
#pragma unroll
    for (int i = 0; i < 8; ++i) Pb[s][i] = base[poff + (unsigned)i * 16384u];
    lsb[s] = base[131072u + poff];
    nmb[s] = base[147456u + ((unsigned)b << 1)];
  };

  loadChunk(0, 0); loadChunk(1, 1); loadChunk(2, 2);
  loadChunk(3, 3); loadChunk(4, 4);

  float lm_next;
  {
    float t0 = lsb[0];
    t0 = fmaxf(t0, __shfl_xor(t0, 1, 64));
    t0 = fmaxf(t0, __shfl_xor(t0, 2, 64));
    t0 = fmaxf(t0, __shfl_xor(t0, 4, 64));
    lm_next = t0;
  }

#pragma unroll
  for (int c = 0; c < 32; ++c){
    const int s = c % 6;                   // static under full unroll
    if (c + 5 < 32) loadChunk(c + 5, (c + 5) % 6);

    const float lm = lm_next;
    const float w = a * fexp2(lsb[s] - lm);

    // next chunk's lm: depends only on prefetched lsb -> overlaps acc chain
    if (c + 1 < 32){
      float t1 = lsb[(c + 1) % 6];
      t1 = fmaxf(t1, __shfl_xor(t1, 1, 64));
      t1 = fmaxf(t1, __shfl_xor(t1, 2, 64));
      t1 = fmaxf(t1, __shfl_xor(t1, 4, 64));
      lm_next = t1;
    }

    // alpha'[j] = sum_i w_i * P[col i][row j]
    float acc = 0.f;
#pragma unroll
    for (int i = 0; i < 8; ++i)
      acc += __shfl(w, gbase + i, 64) * Pb[s][i];

    lZ2 += lm;
    if (c & 1){                            // renorm every 2nd chunk (exact)
      float m2 = acc;
      m2 = fmaxf(m2, __shfl_xor(m2, 1, 64));
      m2 = fmaxf(m2, __shfl_xor(m2, 2, 64));
      m2 = fmaxf(m2, __shfl_xor(m2, 4, 64));
      a = acc * __builtin_amdgcn_rcpf(m2);
      lZ2 += flog2(m2);
    } else {
      a = acc;                             // bounded; folded into next log2
    }
    num += nmb[s];
  }

  float t = a * fexp2(endt[j] * LOG2E);
  t += __shfl_xor(t, 1, 64);
  t += __shfl_xor(t, 2, 64);
  t += __shfl_xor(t, 4, 64);
  const float denom = (flog2(t) + lZ2) * LN2;

  float contrib = (j == 0) ? (denom - num) * (1.0f / 2048.0f) : 0.f;
  contrib += __shfl_xor(contrib, 8, 64);
  contrib += __shfl_xor(contrib, 16, 64);
  contrib += __shfl_xor(contrib, 32, 64);
  if (lane == 0) atomicAdd(out, contrib);
}

extern "C" void kernel_launch(void* const* d_in, const int* in_sizes, int n_in,
                              void* d_out, int out_size, void* d_ws, size_t ws_size,
                              hipStream_t stream) {
  const float* em    = (const float*)d_in[0];
  const float* trans = (const float*)d_in[1];
  const float* strt  = (const float*)d_in[2];
  const float* endt  = (const float*)d_in[3];
  const int*   tags  = (const int*)d_in[4];
  float* out = (float*)d_out;

  // out is zeroed by crf_phase1 block 0 (stream order precedes phase2 atomics)
  // C=32 chunks of S=64 steps; 65536 (b,c) pairs, 4 per wave -> 4096 blocks of 256
  crf_phase1<<<4096, 256, 0, stream>>>(em, trans, endt, tags, (float*)d_ws, out);
  // 256 one-wave blocks: one scan-wave per CU; 32-iteration serial combine
  crf_phase2<<<256, 64, 0, stream>>>(em, strt, endt, tags, (const float*)d_ws, out);
}

// Round 11
// 228.980 us; speedup vs baseline: 1.0881x; 1.0305x over previous
//
#include <hip/hip_runtime.h>
#include <stdint.h>

typedef float  v4f __attribute__((ext_vector_type(4)));
typedef short  v4s __attribute__((ext_vector_type(4)));

#define LOG2E 1.44269504088896340736f
#define LN2   0.69314718055994530942f

static __device__ __forceinline__ float fexp2(float x){ return __builtin_amdgcn_exp2f(x); }
static __device__ __forceinline__ float flog2(float x){ return __builtin_amdgcn_logf(x); }

// pack two f32 -> two bf16 (round-half-up) via v_perm — PROVEN in R1-R4.
// Kept for afrag init (off hot path; reused every step so keep the rounding).
static __device__ __forceinline__ unsigned pkbf(float a, float b){
  unsigned ua = __float_as_uint(a) + 0x8000u;
  unsigned ub = __float_as_uint(b) + 0x8000u;
  return __builtin_amdgcn_perm(ub, ua, 0x07060302u);
}

// Truncating bf16 pack (R14, proven absmax 0.0): 1 v_perm per pair.
// (v_cvt_pk_bf16_f32 NaN'd through BOTH builtin (R5) and asm (R13) — banned.)
static __device__ __forceinline__ v4s pack4(const v4f& m){
  union { unsigned u[2]; v4s s; } t;
  t.u[0] = __builtin_amdgcn_perm(__float_as_uint(m.y), __float_as_uint(m.x), 0x07060302u);
  t.u[1] = __builtin_amdgcn_perm(__float_as_uint(m.w), __float_as_uint(m.z), 0x07060302u);
  return t.s;
}

static __device__ __forceinline__ v4f mfma16(v4s a, v4s b, v4f c){
#if __has_builtin(__builtin_amdgcn_mfma_f32_16x16x16bf16_1k)
  return __builtin_amdgcn_mfma_f32_16x16x16bf16_1k(a, b, c, 0, 0, 0);
#else
  v4f r = c;
  asm("s_nop 1\n\tv_mfma_f32_16x16x16_bf16 %0, %1, %2, %0\n\ts_nop 7\n\ts_nop 1"
      : "+v"(r) : "v"(a), "v"(b));
  return r;
#endif
}

static __device__ __forceinline__ float sel4(const v4f& e4, int s){
  float a = (s & 1) ? e4.y : e4.x;
  float c = (s & 1) ? e4.w : e4.z;
  return (s & 2) ? c : a;
}

// ---------------- Phase 1 ----------------
// R7 structure + R14 truncating pack + R15 6-deep load prefetch.
// MODEL (R14 post-mortem): latency-bound with insufficient MLP. Counters:
// VALU cut -> no time change (not issue-bound); BW 1.1 TB/s of 6.3 achievable
// (not BW-bound); nothing saturated; waves resident but stalled. Little's law:
// ~13 waves x 9 outstanding loads x ~20B / 900cyc ~= the measured 4.5 B/cyc/CU.
// Fix: 6-buffer loadK rotation (18 outstanding loads/wave, ~2x in-flight
// bytes). +18 VGPR -> ~62, still <=64: no occupancy step, no spill.
// One chain per wave: 4 (batch,chunk) 8x8 transfer-matrix products via one
// 16x16x16 bf16 MFMA (blockdiag(E^T,E^T), 2x2 column-octets).
// Lane roles: n=lane&15, q=lane>>4, qr=q&1 (row half r0=4*qr), cn=n&7 (column),
// matrix mm=((q>>1)<<1)|(n>>3). Recurrence P' = diag(exp(em_t)) * E^T * P.
// D (C-layout) == next B (B-layout) -> zero-shuffle feedback.
// exps for block kb+1 computed+written to the LDS parity slot during block kb.
// Per-wave DS ops are in-order: no barrier. Masks from one per-kb __ballot
// (tags monotone); wave-uniform triage (MFMA always full-EXEC); masked body
// is per-lane cndmask; wave-uniform dead-break.

template<bool MASKED>
__device__ __forceinline__ void chunk_loop(
    const float* __restrict__ emb, const int* __restrict__ tgb, int c,
    const float* s_trans, const float* s_end, float* s_slot,
    v4s afrag, int qr, int r0, int cn, bool lastChunk,
    v4f& master, v4s& bfrag, float& lZ, float& num)
{
  v4f eo[6]; int tc[6], tp[6];

  auto loadK = [&](int kb, int buf){
    const int t0 = kb << 3;
    eo[buf] = *(const v4f*)(emb + (size_t)(t0 + cn) * 8u);
    tc[buf] = tgb[t0 + cn];
    int ip = t0 + cn - 1;
    if (c == 0 && ip < 0) ip = 0;        // global t=0: value unused
    tp[buf] = tgb[ip];
  };

  auto expwrite = [&](const v4f& e, int par){
    v4f ed;
    ed.x = fexp2(e.x * LOG2E); ed.y = fexp2(e.y * LOG2E);
    ed.z = fexp2(e.z * LOG2E); ed.w = fexp2(e.w * LOG2E);
    *(v4f*)(s_slot + (par << 5) + (cn << 2)) = ed;   // ds_write_b128
  };

  // 6-deep prologue: 18 outstanding loads before first use (R15 MLP)
  loadK(0, 0); loadK(1, 1); loadK(2, 2);
  loadK(3, 3); loadK(4, 4); loadK(5, 5);
  expwrite(eo[0], 0);

#pragma unroll
  for (int kb = 0; kb < 8; ++kb){
    const int buf = kb % 6;              // static under full unroll

    // distributed numerator for step t = kb*8 + cn (must precede dead-break:
    // the end_transitions add fires on the first masked step of the batch)
    const bool sk0 = (!MASKED) && (c == 0) && (kb == 0);
    {
      bool act = MASKED ? (tc[buf] != 0) : true;
      if (sk0 && cn == 0) act = false;
      const int s = tc[buf] - 1;
      const float ev = sel4(eo[buf], s);
      num += (act && ((s >> 2) == qr)) ? ev : 0.f;
      const float tv = s_trans[(((tp[buf] - 1) & 7) << 3) + (s & 7)];
      num += (act && (qr == 0)) ? tv : 0.f;
      if (MASKED && (tp[buf] != 0) && (tc[buf] == 0) && (qr == 0))
        num += s_end[tp[buf] - 1];
    }

    // per-kb mask byte from one ballot; tags are monotone -> all-zero kb
    // means every later step is masked too: stop the chunk. Both octets of a
    // matrix see identical bytes, so mb is coherent per matrix.
    unsigned mb = 0xffu;
    bool allAlive = true;                 // wave-uniform
    if (MASKED){
      const unsigned long long bal = __ballot(tc[buf] != 0);
      if (bal == 0ull) break;             // wave-uniform: all 4 matrices dead
      mb = (unsigned)(bal >> (threadIdx.x & 56)) & 0xffu;
      allAlive = (bal == ~0ull);
    }

    // broadcast exps for this block (written one block ago)
    v4f e8[8];
    const float* sl = s_slot + ((kb & 1) << 5);
#pragma unroll
    for (int j = 0; j < 8; ++j) e8[j] = *(const v4f*)(sl + (j << 2));

    // exps for next block -> other parity slot (distance = one full block);
    // deep prefetch of block kb+6 into the just-freed buffer
    if (kb + 1 < 8) expwrite(eo[(kb + 1) % 6], (kb + 1) & 1);
    if (kb + 6 < 8) loadK(kb + 6, (kb + 6) % 6);

    // 8 recurrence steps — branch is wave-uniform; MFMA always full-EXEC
    if (!MASKED || allAlive){
#pragma unroll
      for (int j = 0; j < 8; ++j){
        if (sk0 && j == 0) continue;     // global t=0 handled in phase 2
        v4f zero = {0.f, 0.f, 0.f, 0.f};
        v4f d = mfma16(afrag, bfrag, zero);
        const v4f e = e8[j];
        master.x = d.x * e.x; master.y = d.y * e.y;
        master.z = d.z * e.z; master.w = d.w * e.w;
        bfrag = pack4(master);
      }
    } else {
#pragma unroll
      for (int j = 0; j < 8; ++j){
        v4f zero = {0.f, 0.f, 0.f, 0.f};
        v4f d = mfma16(afrag, bfrag, zero);
        const v4f e = e8[j];
        const bool v = (mb >> j) & 1u;   // per-lane cndmask, no branch
        master.x = v ? d.x * e.x : master.x;
        master.y = v ? d.y * e.y : master.y;
        master.z = v ? d.z * e.z : master.z;
        master.w = v ? d.w * e.w : master.w;
        bfrag = pack4(master);
      }
    }

    if (kb & 1){                          // renorm every 16 steps
      float mx = fmaxf(fmaxf(master.x, master.y), fmaxf(master.z, master.w));
      mx = fmaxf(mx, __shfl_xor(mx, 16, 64));
      const float inv = __builtin_amdgcn_rcpf(mx);
      master.x *= inv; master.y *= inv; master.z *= inv; master.w *= inv;
      lZ += flog2(mx);
      bfrag = pack4(master);
    }
  }

  if (MASKED && lastChunk){
    const int lt = tgb[63];               // tag at global t = L-1
    if ((lt != 0) && (qr == 0) && (cn == 0)) num += s_end[lt - 1];
  }
}

__global__ __launch_bounds__(256, 4)
void crf_phase1(const float* __restrict__ em,
                const float* __restrict__ trans,
                const float* __restrict__ endt,
                const int*   __restrict__ tags,
                float* __restrict__ ws,
                float* __restrict__ out)
{
  const int tid  = threadIdx.x;
  const int lane = tid & 63;
  const int n = lane & 15, q = lane >> 4, qr = q & 1, r0 = qr << 2, cn = n & 7;
  const int mm = ((q >> 1) << 1) | (n >> 3);
  const int p  = (blockIdx.x << 4) + ((tid >> 6) << 2) + mm;
  const int c  = p >> 11;                 // chunk id (S=64, C=32)
  const int bm = p & 2047;                // batch id

  if (blockIdx.x == 0 && tid == 0) out[0] = 0.f;   // replaces memset dispatch

  __shared__ float s_trans[64];
  __shared__ float s_end[8];
  __shared__ float s_e[32 * 68];          // 32 groups x (2 slots x 32 + 4 pad)
  if (tid < 64) s_trans[tid] = trans[tid];
  if (tid < 8)  s_end[tid]  = endt[tid];
  __syncthreads();

  // constant A fragment: blockdiag(E^T, E^T); A[m][k], m=n, k=4q+j
  v4s afrag;
  {
    float av[4];
#pragma unroll
    for (int j = 0; j < 4; ++j){
      const int k = (q << 2) + j;
      float v = 0.f;
      if (n < 8 && k < 8)        v = fexp2(s_trans[k * 8 + n] * LOG2E);
      else if (n >= 8 && k >= 8) v = fexp2(s_trans[(k - 8) * 8 + (n - 8)] * LOG2E);
      av[j] = v;
    }
    union { unsigned u[2]; v4s s; } t;
    t.u[0] = pkbf(av[0], av[1]);
    t.u[1] = pkbf(av[2], av[3]);
    afrag = t.s;
  }

  const float* emb = em   + ((size_t)bm * 2048u + (size_t)c * 64u) * 8u + (unsigned)r0;
  const int*   tgb = tags + (size_t)bm * 2048u + (size_t)c * 64u;
  float* s_slot = &s_e[(tid >> 3) * 68];

  // P = identity (exact in bf16; truncation pack is exact here)
  v4f master;
  master.x = (r0 + 0 == cn) ? 1.f : 0.f;
  master.y = (r0 + 1 == cn) ? 1.f : 0.f;
  master.z = (r0 + 2 == cn) ? 1.f : 0.f;
  master.w = (r0 + 3 == cn) ? 1.f : 0.f;
  v4s bfrag = pack4(master);
  float num = 0.f, lZ = 0.f;

  if (c <= 15){                            // steps < 1024: never masked
    chunk_loop<false>(emb, tgb, c, s_trans, s_end, s_slot,
                      afrag, qr, r0, cn, false, master, bfrag, lZ, num);
  } else {
    const bool fz = (tgb[0] == 0);
    if (__ballot(fz) == ~0ull){            // all 4 pairs fully masked: identity
      const int pv = tgb[-1];
      if ((pv != 0) && (qr == 0) && (cn == 0)) num = s_end[pv - 1];
    } else {
      chunk_loop<true>(emb, tgb, c, s_trans, s_end, s_slot,
                       afrag, qr, r0, cn, (c == 31), master, bfrag, lZ, num);
    }
  }

  // ---- store, [c][entry-pair][b] layout (phase-2 coalescing) ----
  float2* ws2 = ((float2*)ws) + (size_t)c * 40u * 2048u + (unsigned)bm;
  const int e0 = (cn << 3) + r0;           // entry e = col*8 + row (even)
  float2 v01; v01.x = master.x; v01.y = master.y;
  float2 v23; v23.x = master.z; v23.y = master.w;
  ws2[(size_t)(e0 >> 1) * 2048u]       = v01;
  ws2[(size_t)((e0 >> 1) + 1) * 2048u] = v23;
  if (qr == 0)
    ((float*)(ws2 + (size_t)((64 + cn) >> 1) * 2048u))[cn & 1] = lZ;
  num += __shfl_xor(num, 1, 64);
  num += __shfl_xor(num, 2, 64);
  num += __shfl_xor(num, 4, 64);
  num += __shfl_xor(num, 16, 64);
  if (qr == 0 && cn == 0)
    ((float*)(ws2 + (size_t)36 * 2048u))[0] = num;
}

// ---------------- Phase 2: per-batch combine of chunk matrices ----------------
// R10 version verbatim (proven at 235us total): 8 lanes per batch; 256
// one-wave blocks; 5-chunk-deep rotating prefetch (50 outstanding loads under
// the vmcnt limit); lm for c+1 computed during c (off-chain); renorm every
// 2nd chunk with the skipped max folded into the next log2 exactly.
__global__ __launch_bounds__(64)
void crf_phase2(const float* __restrict__ em,
                const float* __restrict__ strt,
                const float* __restrict__ endt,
                const int*   __restrict__ tags,
                const float* __restrict__ ws,
                float* __restrict__ out)
{
  const int tid  = threadIdx.x;
  const int lane = tid & 63;
  const int gt = (blockIdx.x << 6) + tid;
  const int b = gt >> 3;                   // batch
  const int j = gt & 7;                    // alpha row
  const int gbase = lane & 56;             // first lane of this batch's group

  const unsigned poff = ((unsigned)(j >> 1) << 12) + (unsigned)(j & 1) + ((unsigned)b << 1);
  const float* wsf = ws;

  const float al = strt[j] + em[(size_t)b * 16384u + (unsigned)j];
  const int s0 = tags[(size_t)b * 2048u] - 1;       // t=0 always valid
  float num = __shfl(al, gbase + s0, 64);           // strt[s0] + em0[s0]

  float mx = al;
  mx = fmaxf(mx, __shfl_xor(mx, 1, 64));
  mx = fmaxf(mx, __shfl_xor(mx, 2, 64));
  mx = fmaxf(mx, __shfl_xor(mx, 4, 64));
  float a = fexp2((al - mx) * LOG2E);
  float lZ2 = mx * LOG2E;

  float Pb[6][8], lsb[6], nmb[6];
  auto loadChunk = [&](int c, int s){
    const float* base = wsf + (size_t)c * 163840u;
#pragma unroll
    for (int i = 0; i < 8; ++i) Pb[s][i] = base[poff + (unsigned)i * 16384u];
    lsb[s] = base[131072u + poff];
    nmb[s] = base[147456u + ((unsigned)b << 1)];
  };

  loadChunk(0, 0); loadChunk(1, 1); loadChunk(2, 2);
  loadChunk(3, 3); loadChunk(4, 4);

  float lm_next;
  {
    float t0 = lsb[0];
    t0 = fmaxf(t0, __shfl_xor(t0, 1, 64));
    t0 = fmaxf(t0, __shfl_xor(t0, 2, 64));
    t0 = fmaxf(t0, __shfl_xor(t0, 4, 64));
    lm_next = t0;
  }

#pragma unroll
  for (int c = 0; c < 32; ++c){
    const int s = c % 6;                   // static under full unroll
    if (c + 5 < 32) loadChunk(c + 5, (c + 5) % 6);

    const float lm = lm_next;
    const float w = a * fexp2(lsb[s] - lm);

    // next chunk's lm: depends only on prefetched lsb -> overlaps acc chain
    if (c + 1 < 32){
      float t1 = lsb[(c + 1) % 6];
      t1 = fmaxf(t1, __shfl_xor(t1, 1, 64));
      t1 = fmaxf(t1, __shfl_xor(t1, 2, 64));
      t1 = fmaxf(t1, __shfl_xor(t1, 4, 64));
      lm_next = t1;
    }

    // alpha'[j] = sum_i w_i * P[col i][row j]
    float acc = 0.f;
#pragma unroll
    for (int i = 0; i < 8; ++i)
      acc += __shfl(w, gbase + i, 64) * Pb[s][i];

    lZ2 += lm;
    if (c & 1){                            // renorm every 2nd chunk (exact)
      float m2 = acc;
      m2 = fmaxf(m2, __shfl_xor(m2, 1, 64));
      m2 = fmaxf(m2, __shfl_xor(m2, 2, 64));
      m2 = fmaxf(m2, __shfl_xor(m2, 4, 64));
      a = acc * __builtin_amdgcn_rcpf(m2);
      lZ2 += flog2(m2);
    } else {
      a = acc;                             // bounded; folded into next log2
    }
    num += nmb[s];
  }

  float t = a * fexp2(endt[j] * LOG2E);
  t += __shfl_xor(t, 1, 64);
  t += __shfl_xor(t, 2, 64);
  t += __shfl_xor(t, 4, 64);
  const float denom = (flog2(t) + lZ2) * LN2;

  float contrib = (j == 0) ? (denom - num) * (1.0f / 2048.0f) : 0.f;
  contrib += __shfl_xor(contrib, 8, 64);
  contrib += __shfl_xor(contrib, 16, 64);
  contrib += __shfl_xor(contrib, 32, 64);
  if (lane == 0) atomicAdd(out, contrib);
}

extern "C" void kernel_launch(void* const* d_in, const int* in_sizes, int n_in,
                              void* d_out, int out_size, void* d_ws, size_t ws_size,
                              hipStream_t stream) {
  const float* em    = (const float*)d_in[0];
  const float* trans = (const float*)d_in[1];
  const float* strt  = (const float*)d_in[2];
  const float* endt  = (const float*)d_in[3];
  const int*   tags  = (const int*)d_in[4];
  float* out = (float*)d_out;

  // out is zeroed by crf_phase1 block 0 (stream order precedes phase2 atomics)
  // C=32 chunks of S=64 steps; 65536 (b,c) pairs, 4 per wave -> 4096 blocks of 256
  crf_phase1<<<4096, 256, 0, stream>>>(em, trans, endt, tags, (float*)d_ws, out);
  // 256 one-wave blocks: one scan-wave per CU; 32-iteration serial combine
  crf_phase2<<<256, 64, 0, stream>>>(em, strt, endt, tags, (const float*)d_ws, out);
}